// Round 3
// baseline (2795.328 us; speedup 1.0000x reference)
//
#include <hip/hip_runtime.h>
#include <stdint.h>

#define NN 100000      // nodes
#define NE 1600000     // edges
#define MAXDEG 64      // Poisson(16): P(deg>64) ~ 1e-19, safe cap
#define NSLICE 8       // XCD count for build slicing
#define SLICE_SZ 12500 // nodes per build slice
#define CHUNK 6400     // edges per build block
#define PHASES 16      // gather phase-slices
#define PSLICE 6250    // nodes per phase-slice (16 * 6250 = 100000)
#define GBLK 512       // gather blocks (2 per CU, fully resident)

typedef __attribute__((ext_vector_type(8))) short short8;
typedef __attribute__((ext_vector_type(4))) float f32x4;

__device__ __forceinline__ float bflo(unsigned v) { return __uint_as_float(v << 16); }
__device__ __forceinline__ float bfhi(unsigned v) { return __uint_as_float(v & 0xffff0000u); }
__device__ __forceinline__ unsigned short f2bf(float f) {   // round-to-nearest-even
  unsigned u = __float_as_uint(f);
  u += 0x7fff + ((u >> 16) & 1);
  return (unsigned short)(u >> 16);
}

// ---- XCD-sliced bucket build (UNCHANGED, proven) ----
__global__ __launch_bounds__(256) void build_buckets(const int* __restrict__ src,
                                                     const int* __restrict__ dst,
                                                     int* __restrict__ cnt,
                                                     int* __restrict__ buck) {
  const int slice = blockIdx.x & (NSLICE - 1);
  const int chunk = blockIdx.x >> 3;
  const int c0 = chunk * CHUNK;
  const int lo = slice * SLICE_SZ, hi = lo + SLICE_SZ;
  for (int e = c0 + (int)threadIdx.x * 4; e < c0 + CHUNK; e += 1024) {
    int4 d = *(const int4*)(dst + e);
    int4 s = *(const int4*)(src + e);
    if (d.x >= lo && d.x < hi) { int p = atomicAdd(&cnt[d.x], 1); if (p < MAXDEG) buck[d.x * MAXDEG + p] = s.x; }
    if (d.y >= lo && d.y < hi) { int p = atomicAdd(&cnt[d.y], 1); if (p < MAXDEG) buck[d.y * MAXDEG + p] = s.y; }
    if (d.z >= lo && d.z < hi) { int p = atomicAdd(&cnt[d.z], 1); if (p < MAXDEG) buck[d.z * MAXDEG + p] = s.z; }
    if (d.w >= lo && d.w < hi) { int p = atomicAdd(&cnt[d.w], 1); if (p < MAXDEG) buck[d.w * MAXDEG + p] = s.w; }
  }
}

// ---- sort each node's bucket by source phase-slice; emit u16 local ids + u8 offsets ----
// One wave per node: ballot counting-sort over 16 keys.
__global__ __launch_bounds__(256) void sort_buckets(const int* __restrict__ cnt,
                                                    const int* __restrict__ buckT,
                                                    unsigned short* __restrict__ buck4,
                                                    unsigned char* __restrict__ offb) {
  const int node = blockIdx.x * 4 + (threadIdx.x >> 6);
  if (node >= NN) return;
  const int lane = threadIdx.x & 63;
  const int d = min(cnt[node], MAXDEG);
  const unsigned e = (unsigned)buckT[(size_t)node * 64 + lane];
  const bool valid = lane < d;
  // slice = e / 6250 for e < 100000 via magic mul (verified exact for all boundaries)
  unsigned s = (e * 42950u) >> 28;
  if (!valid) s = 31u;                       // exclude garbage from ballots
  unsigned long long mk[16];
#pragma unroll
  for (int k = 0; k < 16; k++) mk[k] = __ballot(s == (unsigned)k);
  int base = 0;
#pragma unroll
  for (int k = 0; k < 16; k++) if ((unsigned)k < s) base += __popcll(mk[k]);
  if (valid) {
    unsigned long long below = mk[s & 15] & ((1ull << lane) - 1ull);
    int rank = base + __popcll(below);
    buck4[(size_t)node * 64 + rank] = (unsigned short)(e - s * PSLICE);
  }
  if (lane < 16) {
    int st = 0;
    for (int k = 0; k < lane; k++) st += __popcll(mk[k]);
    offb[node * 16 + lane] = (unsigned char)st;
  }
}

// ---- f32 -> channel-split bf16 tables: xlo = ch[0,64), xhi = ch[64,128), 128B rows ----
__global__ __launch_bounds__(256) void to_bf16split(const float* __restrict__ x,
                                                    unsigned short* __restrict__ xlo,
                                                    unsigned short* __restrict__ xhi) {
  int i = blockIdx.x * 256 + threadIdx.x;    // over NN*32 float4s
  if (i >= NN * 32) return;
  float4 v = ((const float4*)x)[i];
  int n = i >> 5, c = i & 31;
  uint2 o;
  o.x = ((unsigned)f2bf(v.y) << 16) | f2bf(v.x);
  o.y = ((unsigned)f2bf(v.w) << 16) | f2bf(v.z);
  unsigned short* t = (c < 16) ? xlo : xhi;
  int cc = c & 15;
  *(uint2*)(t + (size_t)n * 64 + cc * 4) = o;
}

// ---- one-time W transpose -> k-major bf16 (UNCHANGED) ----
__global__ __launch_bounds__(256) void transpose_w(const float* __restrict__ W1l,
                                                   const float* __restrict__ W1r,
                                                   const float* __restrict__ W2l,
                                                   const float* __restrict__ W2r,
                                                   unsigned short* __restrict__ WT1,
                                                   unsigned short* __restrict__ WT2) {
  int t = blockIdx.x * 256 + threadIdx.x;
  if (t < 128 * 256) {
    int m = t >> 8, k = t & 255;
    float v = (k < 128) ? W1l[k * 128 + m] : W1r[(k - 128) * 128 + m];
    WT1[t] = f2bf(v);
  } else {
    int i = t - 128 * 256;
    if (i < 64 * 256) {
      int m = i >> 8, k = i & 255;
      float v = (k < 128) ? W2l[k * 64 + m] : W2r[(k - 128) * 64 + m];
      WT2[i] = f2bf(v);
    }
  }
}

// ---- warm helpers: sequential L2 fills, kept alive via xor-sink (no DCE, rule #17) ----
__device__ __forceinline__ unsigned warm_slice(const unsigned* tbl, int s, int unit, int lane) {
  // slice s = PSLICE rows * 32 u32 = 200000 u32 = 50000 uint4; 256 units per XCD
  const uint4* p = (const uint4*)tbl + (size_t)s * 50000 + (size_t)unit * 196;
  const int lim = min(196, 50000 - unit * 196);
  unsigned acc = 0;
#pragma unroll
  for (int it = 0; it < 4; it++) {
    int idx = it * 64 + lane;
    if (idx < lim) { uint4 v = p[idx]; acc ^= v.x ^ v.y ^ v.z ^ v.w; }
  }
  return acc;
}
__device__ __forceinline__ unsigned warm_range(const unsigned short* a, const unsigned short* b,
                                               int r0, int r1, int wv, int lane) {
  const int n16 = (r1 - r0) * 8;             // uint4 per table
  const uint4* pa = (const uint4*)(a + (size_t)r0 * 64);
  const uint4* pb = (const uint4*)(b + (size_t)r0 * 64);
  unsigned acc = 0;
#pragma unroll
  for (int it = 0; it < 7; it++) {
    int idx = (it * 4 + wv) * 64 + lane;
    if (idx < n16) {
      uint4 v1 = pa[idx]; uint4 v2 = pb[idx];
      acc ^= v1.x ^ v1.y ^ v1.z ^ v1.w ^ v2.x ^ v2.y ^ v2.z ^ v2.w;
    }
  }
  return acc;
}

// ---- STREAMED fused layer. 512 fully-resident blocks; each owns ~196 rows with f32
// accumulators in LDS. Two channel-half passes x 16 source-slice phases. Per phase:
// warm-stream next slice (sequential compulsory fills), gather current slice (L2 hits).
// Barrier-free: rows are wave-private (lr = wv + 4*i). MFMA/epilogue structure preserved.
template <int M, bool RELU, bool OUT16>
__global__ __launch_bounds__(256, 2) void sage_stream(
    const unsigned short* __restrict__ tlo, const unsigned short* __restrict__ thi,
    const int* __restrict__ cnt, const unsigned short* __restrict__ buck4,
    const unsigned char* __restrict__ offb, const unsigned short* __restrict__ WT,
    const float* __restrict__ bias, unsigned short* __restrict__ out_lo,
    unsigned short* __restrict__ out_hi, float* __restrict__ out_f) {
  __shared__ float F[196 * 64];                  // f32 accum, 64 ch per pass, 256B rows
  __shared__ unsigned short AGG[196 * 72];       // drained lo-half agg bf16, 144B pitch

  const int tid = threadIdx.x, lane = tid & 63, wv = tid >> 6;
  const int bid = blockIdx.x;
  const int rb0 = (bid * NN) / GBLK, rb1 = ((bid + 1) * NN) / GBLK;
  const int nrows = rb1 - rb0;
  const int nmy = (nrows - wv + 3) >> 2;         // my rows: lr = wv + 4*i
  const int grp2 = lane >> 5, cl32 = lane & 31;
  const unsigned* buck4w = (const unsigned*)buck4;
  const int unit = (bid >> 3) * 4 + wv;          // warm unit within XCD cohort (0..255)

  for (int i = 0; i < nmy; i++) F[(wv + i * 4) * 64 + lane] = 0.f;

  unsigned wpend = 0;
  for (int half = 0; half < 2; half++) {
    const unsigned* tbl = (const unsigned*)(half ? thi : tlo);
    { unsigned a = warm_slice(tbl, 0, unit, lane);   // prologue warm
      asm volatile("" :: "v"(wpend)); wpend = a; }
    for (int s = 0; s < PHASES; s++) {
      unsigned wnew;
      if (s + 1 < PHASES) wnew = warm_slice(tbl, s + 1, unit, lane);
      else if (half == 0) wnew = warm_slice((const unsigned*)thi, 0, unit, lane);
      else                wnew = warm_range(tlo, thi, rb0, rb1, wv, lane);

      const int sbase = s * PSLICE;
      for (int rb = 0; rb < nmy; rb += 8) {
        unsigned ia[8], ib[8], dvv[8];
        int css[8], oo0[8], lrr[8];
#pragma unroll
        for (int k = 0; k < 8; k++) {
          int myi = rb + k;
          bool rok = myi < nmy;
          int lr = rok ? wv + myi * 4 : wv;
          lrr[k] = lr;
          int node = rb0 + lr;
          int o0 = offb[node * 16 + s];
          int o1 = (s == PHASES - 1) ? min(cnt[node], MAXDEG) : (int)offb[node * 16 + s + 1];
          int cs = rok ? o1 - o0 : 0;
          css[k] = cs; oo0[k] = o0;
          int wi = (node * 64 + (o0 & ~1)) >> 1;     // aligned u32 window (4 slots)
          ia[k] = buck4w[wi]; ib[k] = buck4w[wi + 1];
          int jj = (o0 & 1) + grp2;                  // 0..2
          unsigned wsel = (jj & 2) ? ib[k] : ia[k];
          unsigned ed = (wsel >> ((jj & 1) << 4)) & 0xFFFFu;
          dvv[k] = tbl[(size_t)(sbase + (int)ed) * 32 + cl32];   // in-ws even if garbage
        }
#pragma unroll
        for (int k = 0; k < 8; k++) {
          int cs = css[k];
          if (cs <= 0) continue;                     // wave-uniform
          unsigned v = dvv[k];
          bool val = grp2 < cs;
          float b0 = val ? bflo(v) : 0.f;
          float b1 = val ? bfhi(v) : 0.f;
          int node = rb0 + lrr[k];
          for (int gg = 2; gg < cs; gg += 2) {       // rare mop-up (P(cs>2) ~ 8%)
            int jj2 = oo0[k] + gg + grp2;
            int lastj = oo0[k] + cs - 1;
            unsigned ed2 = buck4[(size_t)node * 64 + min(jj2, lastj)];
            unsigned v2 = tbl[(size_t)(sbase + (int)ed2) * 32 + cl32];
            if (gg + grp2 < cs) { b0 += bflo(v2); b1 += bfhi(v2); }
          }
          b0 += __shfl_xor(b0, 32, 64);
          b1 += __shfl_xor(b1, 32, 64);
          if (lane < 32) {
            float2* fp = (float2*)&F[lrr[k] * 64 + lane * 2];
            float2 t = *fp; t.x += b0; t.y += b1; *fp = t;
          }
        }
      }
      asm volatile("" :: "v"(wpend)); wpend = wnew;  // retire prev warm (already landed)
    }
    // drain this half's accumulators (per-wave private; no barrier needed)
    for (int i = 0; i < nmy; i++) {
      int lr = wv + i * 4, node = rb0 + lr;
      float inv = 1.f / (float)max(cnt[node], 1);
      float v = F[lr * 64 + lane] * inv;
      if (half == 0) { AGG[lr * 72 + lane] = f2bf(v); F[lr * 64 + lane] = 0.f; }
      else           { ((unsigned short*)F)[lr * 128 + lane] = f2bf(v); }
    }
  }
  asm volatile("" :: "v"(wpend));

  // ---- MFMA: A = [aggLo | aggHi | rootLo | rootHi], B = k-major WT (L2-hot) ----
  const int m = lane & 15, q = lane >> 4;
  const unsigned short* FB = (const unsigned short*)F;
  const int ngroups = (nmy + 15) >> 4;
  for (int g = 0; g < ngroups; g++) {
    int myi = g * 16 + m;
    int lr = wv + min(myi, nmy - 1) * 4;       // clamp; invalid rows masked at store
    int node = rb0 + lr;
    f32x4 acc[M / 16];
#pragma unroll
    for (int cc = 0; cc < M / 16; cc++) acc[cc] = {0.f, 0.f, 0.f, 0.f};
#pragma unroll
    for (int ks = 0; ks < 8; ks++) {
      short8 a;
      int off16 = ((ks & 1) << 5) + (q << 3);
      if (ks < 2)      a = *(const short8*)&AGG[lr * 72 + off16];
      else if (ks < 4) a = *(const short8*)&FB[lr * 128 + off16];
      else if (ks < 6) a = *(const short8*)(tlo + (size_t)node * 64 + off16);
      else             a = *(const short8*)(thi + (size_t)node * 64 + off16);
#pragma unroll
      for (int cc = 0; cc < M / 16; cc++) {
        short8 b = *(const short8*)(WT + (size_t)(cc * 16 + m) * 256 + ks * 32 + q * 8);
        acc[cc] = __builtin_amdgcn_mfma_f32_16x16x32_bf16(a, b, acc[cc], 0, 0, 0);
      }
    }
    // restage through my (dead) F rows, then full-line-ish stores
#pragma unroll
    for (int cc = 0; cc < M / 16; cc++) {
      int col = cc * 16 + m;
      float bc = bias[col];
#pragma unroll
      for (int r = 0; r < 4; r++) {
        int myir = g * 16 + q * 4 + r;          // D[row=q*4+r][col=m]
        float v = acc[cc][r] + bc;
        if (RELU) v = fmaxf(v, 0.f);
        if (myir < nmy) {
          int lr2 = wv + myir * 4;
          if (OUT16) ((unsigned short*)F)[lr2 * 128 + col] = f2bf(v);
          else       F[lr2 * 64 + col] = v;
        }
      }
    }
#pragma unroll
    for (int it = 0; it < 8; it++) {            // 16 rows x (32 lanes * 8B)
      int rr = it * 2 + (lane >> 5);
      int myir = g * 16 + rr;
      int cho = lane & 31;
      if (myir < nmy) {
        int lr2 = wv + myir * 4;
        int node2 = rb0 + lr2;
        if (OUT16) {
          uint2 vv = *(const uint2*)&((const unsigned short*)F)[lr2 * 128 + cho * 4];
          unsigned short* dp = (cho < 16) ? (out_lo + (size_t)node2 * 64 + cho * 4)
                                          : (out_hi + (size_t)node2 * 64 + (cho - 16) * 4);
          *(uint2*)dp = vv;
        } else {
          uint2 vv = *(const uint2*)&((const unsigned*)F)[lr2 * 64 + cho * 2];
          *(uint2*)((unsigned*)out_f + (size_t)node2 * 64 + cho * 2) = vv;
        }
      }
    }
  }
}

extern "C" void kernel_launch(void* const* d_in, const int* in_sizes, int n_in,
                              void* d_out, int out_size, void* d_ws, size_t ws_size,
                              hipStream_t stream) {
  const float* x   = (const float*)d_in[0];
  const int*   ei  = (const int*)d_in[1];
  const float* W1l = (const float*)d_in[2];
  const float* b1  = (const float*)d_in[3];
  const float* W1r = (const float*)d_in[4];
  const float* W2l = (const float*)d_in[5];
  const float* b2  = (const float*)d_in[6];
  const float* W2r = (const float*)d_in[7];
  float* out = (float*)d_out;

  // ws (<= 66.2MB, under proven 77.4MB budget):
  // cnt 0.5 | buckT 25.6 (reused as hlo|hhi after sort) | buck4 12.8 | offb 1.6 |
  // xlo 12.8 | xhi 12.8 | WT1 | WT2
  char* ws = (char*)d_ws;
  int* cnt  = (int*)ws;                                   ws += (512 << 10);
  int* buckT = (int*)ws;                                  ws += (size_t)NN * 64 * 4;
  unsigned short* buck4 = (unsigned short*)ws;            ws += (size_t)NN * 64 * 2;
  unsigned char* offb = (unsigned char*)ws;               ws += (size_t)NN * 16;
  unsigned short* xlo = (unsigned short*)ws;              ws += (size_t)NN * 64 * 2;
  unsigned short* xhi = (unsigned short*)ws;              ws += (size_t)NN * 64 * 2;
  unsigned short* WT1 = (unsigned short*)ws;              ws += 128 * 256 * 2;
  unsigned short* WT2 = (unsigned short*)ws;              ws += 64 * 256 * 2;
  unsigned short* hlo = (unsigned short*)buckT;           // alias: buckT dead after sort
  unsigned short* hhi = hlo + (size_t)NN * 64;

  const int* src = ei;        // edge_index[0]
  const int* dst = ei + NE;   // edge_index[1]

  hipMemsetAsync(cnt, 0, (size_t)NN * 4, stream);
  build_buckets<<<NSLICE * (NE / CHUNK), 256, 0, stream>>>(src, dst, cnt, buckT);
  sort_buckets<<<(NN + 3) / 4, 256, 0, stream>>>(cnt, buckT, buck4, offb);
  to_bf16split<<<(NN * 32 + 255) / 256, 256, 0, stream>>>(x, xlo, xhi);
  transpose_w<<<192, 256, 0, stream>>>(W1l, W1r, W2l, W2r, WT1, WT2);

  // layer 1: h = relu([mean|x] @ [W1l;W1r] + b1), bf16 split tables
  sage_stream<128, true, true><<<GBLK, 256, 0, stream>>>(
      xlo, xhi, cnt, buck4, offb, WT1, b1, hlo, hhi, nullptr);

  // layer 2: out = [mean|h] @ [W2l;W2r] + b2, f32
  sage_stream<64, false, false><<<GBLK, 256, 0, stream>>>(
      hlo, hhi, cnt, buck4, offb, WT2, b2, nullptr, nullptr, out);
}

// Round 4
// 387.962 us; speedup vs baseline: 7.2052x; 7.2052x over previous
//
#include <hip/hip_runtime.h>
#include <stdint.h>

#define NN 100000      // nodes
#define NE 1600000     // edges
#define MAXDEG 64      // Poisson(16): P(deg>64) ~ 1e-19, safe cap
#define NSLICE 8       // XCD count; slice = blockIdx & 7 (perf heuristic only)
#define SLICE_SZ 12500 // nodes per slice
#define CHUNK 6400     // edges per block; NE/CHUNK = 250 chunks per slice

typedef __attribute__((ext_vector_type(8))) short short8;
typedef __attribute__((ext_vector_type(4))) float f32x4;

__device__ __forceinline__ float bflo(unsigned v) { return __uint_as_float(v << 16); }
__device__ __forceinline__ float bfhi(unsigned v) { return __uint_as_float(v & 0xffff0000u); }
__device__ __forceinline__ unsigned short f2bf(float f) {   // round-to-nearest-even
  unsigned u = __float_as_uint(f);
  u += 0x7fff + ((u >> 16) & 1);
  return (unsigned short)(u >> 16);
}

// ---- XCD-sliced bucket build: per-XCD write region 3.2MB -> L2-resident ----
__global__ __launch_bounds__(256) void build_buckets(const int* __restrict__ src,
                                                     const int* __restrict__ dst,
                                                     int* __restrict__ cnt,
                                                     int* __restrict__ buck) {
  const int slice = blockIdx.x & (NSLICE - 1);
  const int chunk = blockIdx.x >> 3;
  const int c0 = chunk * CHUNK;
  const int lo = slice * SLICE_SZ, hi = lo + SLICE_SZ;
  for (int e = c0 + (int)threadIdx.x * 4; e < c0 + CHUNK; e += 1024) {
    int4 d = *(const int4*)(dst + e);
    int4 s = *(const int4*)(src + e);
    if (d.x >= lo && d.x < hi) { int p = atomicAdd(&cnt[d.x], 1); if (p < MAXDEG) buck[d.x * MAXDEG + p] = s.x; }
    if (d.y >= lo && d.y < hi) { int p = atomicAdd(&cnt[d.y], 1); if (p < MAXDEG) buck[d.y * MAXDEG + p] = s.y; }
    if (d.z >= lo && d.z < hi) { int p = atomicAdd(&cnt[d.z], 1); if (p < MAXDEG) buck[d.z * MAXDEG + p] = s.z; }
    if (d.w >= lo && d.w < hi) { int p = atomicAdd(&cnt[d.w], 1); if (p < MAXDEG) buck[d.w * MAXDEG + p] = s.w; }
  }
}

// ---- f32 -> packed bf16x2 (float4 per thread) ----
__global__ __launch_bounds__(256) void to_bf16(const float* __restrict__ x,
                                               unsigned* __restrict__ xb) {
  int i = blockIdx.x * 256 + threadIdx.x;     // over NN*32
  if (i >= NN * 32) return;
  float4 v = ((const float4*)x)[i];
  uint2 o;
  o.x = ((unsigned)f2bf(v.y) << 16) | f2bf(v.x);
  o.y = ((unsigned)f2bf(v.w) << 16) | f2bf(v.z);
  ((uint2*)xb)[i] = o;
}

// ---- one-time W transpose -> k-major bf16.
// WT1[m][k], m in [0,128), k = [W1l rows | W1r rows] (256 k)   -- unchanged
// WT2p[m][k], m in [0,128): m<64 -> W2l col m, m>=64 -> W2r col m-64; k in [0,128)
__global__ __launch_bounds__(256) void transpose_w(const float* __restrict__ W1l,
                                                   const float* __restrict__ W1r,
                                                   const float* __restrict__ W2l,
                                                   const float* __restrict__ W2r,
                                                   unsigned short* __restrict__ WT1,
                                                   unsigned short* __restrict__ WT2p) {
  int t = blockIdx.x * 256 + threadIdx.x;
  if (t < 128 * 256) {
    int m = t >> 8, k = t & 255;
    float v = (k < 128) ? W1l[k * 128 + m] : W1r[(k - 128) * 128 + m];
    WT1[t] = f2bf(v);
  } else {
    int i = t - 128 * 256;
    if (i < 128 * 128) {
      int m = i >> 7, k = i & 127;
      float v = (m < 64) ? W2l[k * 64 + m] : W2r[k * 64 + (m - 64)];
      WT2p[i] = f2bf(v);
    }
  }
}

// ---- FUSED layer 1 (PROVEN R0 kernel, verbatim): gather-mean into LDS, MFMA.
// Barrier-free: wave wv owns sA rows [wv*16, wv*16+16) exclusively.
template <int M, bool RELU, typename OutT>
__global__ __launch_bounds__(256) void sage_fused(const unsigned* __restrict__ xb,
                                                  const int* __restrict__ cnt,
                                                  const int* __restrict__ buck,
                                                  const unsigned short* __restrict__ WT,
                                                  const float* __restrict__ bias,
                                                  OutT* __restrict__ out) {
  constexpr int LDA = 264;                       // +8 bf16 pad; 528B pitch
  __shared__ unsigned short sA[64][LDA];

  const int t = threadIdx.x;
  const int lane = t & 63;
  const int wv = t >> 6;
  const int node0 = blockIdx.x * 64;
  const int nb = node0 + wv * 16;                // this wave's 16 nodes

  // ---- prefetch: 16 bucket rows + 16 x rows + 16 degrees (all independent) ----
  int slot[16]; unsigned xr[16]; int deg[16];
#pragma unroll
  for (int i = 0; i < 16; i++) {
    int node = nb + i;
    if (node < NN) {                             // lane-uniform branch
      slot[i] = buck[(size_t)node * MAXDEG + lane];
      xr[i]   = xb[(size_t)node * 64 + lane];
      deg[i]  = cnt[node];
    } else { slot[i] = 0; xr[i] = 0u; deg[i] = 0; }
  }

  // ---- gather-mean each of my 16 rows into wave-private LDS ----
#pragma unroll
  for (int i = 0; i < 16; i++) {
    float a0 = 0.f, a1 = 0.f;
    int dcl = min(deg[i], MAXDEG);
    if (dcl > 0) {                               // wave-uniform
      int last = dcl - 1;
      for (int p = 0; p < dcl; p += 16) {
        unsigned v[16];
#pragma unroll
        for (int j = 0; j < 16; j++) {
          int s = __shfl(slot[i], min(p + j, last), 64);
          v[j] = xb[(size_t)s * 64 + lane];      // 256B/row coalesced, no branch
        }
#pragma unroll
        for (int j = 0; j < 16; j++) {
          unsigned vj = (p + j <= last) ? v[j] : 0u;
          a0 += bflo(vj); a1 += bfhi(vj);
        }
      }
    }
    float inv = 1.f / (float)max(deg[i], 1);
    unsigned pk = ((unsigned)f2bf(a1 * inv) << 16) | f2bf(a0 * inv);
    ((unsigned*)&sA[wv * 16 + i][0])[lane]   = pk;      // agg half: k in [0,128)
    ((unsigned*)&sA[wv * 16 + i][128])[lane] = xr[i];   // x half:   k in [128,256)
  }

  // ---- MFMA: A from my LDS rows, B from k-major WT in global (L2-hot) ----
  const int m = lane & 15;
  const int q = lane >> 4;

  f32x4 acc[M / 16];
#pragma unroll
  for (int c = 0; c < M / 16; c++) acc[c] = {0.f, 0.f, 0.f, 0.f};

#pragma unroll
  for (int ks = 0; ks < 8; ks++) {
    short8 a = *(const short8*)&sA[wv * 16 + m][ks * 32 + q * 8];   // A[m][q*8+j]
#pragma unroll
    for (int c = 0; c < M / 16; c++) {
      // B[k=q*8+j][n=c*16+m] = WT[n][k], contiguous 16B in k
      short8 b = *(const short8*)(WT + (size_t)(c * 16 + m) * 256 + ks * 32 + q * 8);
      acc[c] = __builtin_amdgcn_mfma_f32_16x16x32_bf16(a, b, acc[c], 0, 0, 0);
    }
  }

  // ---- epilogue: restage C through my (dead) sA rows -> full-line stores ----
#pragma unroll
  for (int c = 0; c < M / 16; c++) {
    int col = c * 16 + m;
    float bc = bias[col];
#pragma unroll
    for (int r = 0; r < 4; r++) {
      int lr = wv * 16 + q * 4 + r;               // D[row=q*4+r][col=m]
      float v = acc[c][r] + bc;
      if (RELU) v = fmaxf(v, 0.f);
      if constexpr (sizeof(OutT) == 2) sA[lr][col] = f2bf(v);
      else ((float*)&sA[lr][0])[col] = v;
    }
  }
#pragma unroll
  for (int it = 0; it < 4; it++) {
    int idx = it * 64 + lane;                     // 16 rows x 16 chunks of 16B
    int rr = idx >> 4, cc = idx & 15;
    int node = node0 + wv * 16 + rr;
    if (node < NN) {
      uint4 v = *(const uint4*)((const char*)&sA[wv * 16 + rr][0] + cc * 16);
      *(uint4*)((char*)(out + (size_t)node * M) + cc * 16) = v;
    }
  }
}

// ---- layer-2 pre-projection (dense, streamed): p = h@W2l (bf16, 64ch rows),
// out = h@W2r + b2 (f32). Gather then operates on 128B rows (1 line/edge).
__global__ __launch_bounds__(256) void proj2(const unsigned* __restrict__ hb,
                                             const unsigned short* __restrict__ WTp,
                                             const float* __restrict__ b2,
                                             unsigned* __restrict__ p,
                                             float* __restrict__ out) {
  __shared__ unsigned short sA[64][136];          // 272B pitch
  const int lane = threadIdx.x & 63, wv = threadIdx.x >> 6;
  const int node0 = blockIdx.x * 64, nb = node0 + wv * 16;

  // stage my 16 h-rows (streamed, coalesced)
#pragma unroll
  for (int i = 0; i < 16; i++) {
    int node = nb + i;
    unsigned v = (node < NN) ? hb[(size_t)node * 64 + lane] : 0u;
    ((unsigned*)&sA[wv * 16 + i][0])[lane] = v;
  }

  const int m = lane & 15, q = lane >> 4;
  f32x4 acc[8];
#pragma unroll
  for (int cc = 0; cc < 8; cc++) acc[cc] = {0.f, 0.f, 0.f, 0.f};
#pragma unroll
  for (int ks = 0; ks < 4; ks++) {                // K = 128
    short8 a = *(const short8*)&sA[wv * 16 + m][ks * 32 + q * 8];
#pragma unroll
    for (int cc = 0; cc < 8; cc++) {
      short8 b = *(const short8*)(WTp + (size_t)(cc * 16 + m) * 128 + ks * 32 + q * 8);
      acc[cc] = __builtin_amdgcn_mfma_f32_16x16x32_bf16(a, b, acc[cc], 0, 0, 0);
    }
  }

  // p-half (cols 0..63 = h@W2l): restage bf16, store 128B rows
#pragma unroll
  for (int cc = 0; cc < 4; cc++) {
    int col = cc * 16 + m;
#pragma unroll
    for (int r = 0; r < 4; r++) {
      int lr = wv * 16 + q * 4 + r;
      sA[lr][col] = f2bf(acc[cc][r]);
    }
  }
#pragma unroll
  for (int it = 0; it < 2; it++) {                // 16 rows x 8 chunks of 16B
    int idx = it * 64 + lane;
    int rr = idx >> 3, ck = idx & 7;
    int node = nb + rr;
    if (node < NN) {
      uint4 v = *(const uint4*)((const char*)&sA[wv * 16 + rr][0] + ck * 16);
      *(uint4*)((char*)(p + (size_t)node * 32) + ck * 16) = v;
    }
  }
  // r-half (cols 64..127 = h@W2r + b2): restage f32, store 256B rows
#pragma unroll
  for (int cc = 4; cc < 8; cc++) {
    int col = (cc - 4) * 16 + m;
    float bc = b2[col];
#pragma unroll
    for (int r = 0; r < 4; r++) {
      int lr = wv * 16 + q * 4 + r;
      ((float*)&sA[lr][0])[col] = acc[cc][r] + bc;
    }
  }
#pragma unroll
  for (int it = 0; it < 4; it++) {                // 16 rows x 16 chunks of 16B
    int idx = it * 64 + lane;
    int rr = idx >> 4, ck = idx & 15;
    int node = nb + rr;
    if (node < NN) {
      uint4 v = *(const uint4*)((const char*)&sA[wv * 16 + rr][0] + ck * 16);
      *(uint4*)((char*)(out + (size_t)node * 64) + ck * 16) = v;
    }
  }
}

// ---- layer-2 gather: out[i] += mean_j p[j]. 128B rows = 1 line/edge.
// 2 edges per load (g = lane>>5), 32 lanes x u32 (2 ch) per edge.
__global__ __launch_bounds__(256) void gather_add(const unsigned* __restrict__ p,
                                                  const int* __restrict__ cnt,
                                                  const int* __restrict__ buck,
                                                  float* __restrict__ out) {
  const int lane = threadIdx.x & 63, wv = threadIdx.x >> 6;
  const int nb = blockIdx.x * 64 + wv * 16;
  const int g = lane >> 5, c = lane & 31;

  int slot[16]; int deg[16];
#pragma unroll
  for (int i = 0; i < 16; i++) {
    int node = nb + i;
    if (node < NN) {
      slot[i] = buck[(size_t)node * MAXDEG + lane];
      deg[i]  = cnt[node];
    } else { slot[i] = 0; deg[i] = 0; }
  }

#pragma unroll
  for (int i = 0; i < 16; i++) {
    float a0 = 0.f, a1 = 0.f;
    int d = min(deg[i], MAXDEG);
    if (d > 0) {                                  // wave-uniform
      int last = d - 1;
      for (int pp = 0; pp < d; pp += 16) {        // 16 edges per chunk, 8 loads
        unsigned v[8];
#pragma unroll
        for (int j = 0; j < 8; j++) {
          int e = pp + 2 * j + g;
          int s = __shfl(slot[i], e < last ? e : last, 64);
          v[j] = p[(size_t)s * 32 + c];           // 128B/row = 1 line/edge
        }
#pragma unroll
        for (int j = 0; j < 8; j++) {
          int e = pp + 2 * j + g;
          unsigned w = (e <= last) ? v[j] : 0u;
          a0 += bflo(w); a1 += bfhi(w);
        }
      }
      a0 += __shfl_xor(a0, 32, 64);
      a1 += __shfl_xor(a1, 32, 64);
    }
    int node = nb + i;
    if (node < NN && lane < 32) {
      float inv = 1.f / (float)max(deg[i], 1);
      float2* fp = (float2*)(out + (size_t)node * 64 + 2 * c);
      float2 tv = *fp;
      tv.x += a0 * inv; tv.y += a1 * inv;
      *fp = tv;
    }
  }
}

extern "C" void kernel_launch(void* const* d_in, const int* in_sizes, int n_in,
                              void* d_out, int out_size, void* d_ws, size_t ws_size,
                              hipStream_t stream) {
  const float* x   = (const float*)d_in[0];
  const int*   ei  = (const int*)d_in[1];
  const float* W1l = (const float*)d_in[2];
  const float* b1  = (const float*)d_in[3];
  const float* W1r = (const float*)d_in[4];
  const float* W2l = (const float*)d_in[5];
  const float* b2  = (const float*)d_in[6];
  const float* W2r = (const float*)d_in[7];
  float* out = (float*)d_out;

  // ws: cnt 0.5MB | buck 25.6MB | xbf 25.6MB (p aliases, dead after L1) |
  //     hb 25.6MB | WT1 64KB | WT2p 32KB  == proven 77.4MB footprint
  char* ws = (char*)d_ws;
  int* cnt  = (int*)ws;                                   ws += (512 << 10);
  int* buck = (int*)ws;                                   ws += (size_t)NN * MAXDEG * 4;
  unsigned* xbf = (unsigned*)ws;                          ws += (size_t)NN * 64 * 4;
  unsigned* hb = (unsigned*)ws;                           ws += (size_t)NN * 64 * 4;
  unsigned short* WT1 = (unsigned short*)ws;              ws += 128 * 256 * 2;
  unsigned short* WT2p = (unsigned short*)ws;             ws += 128 * 128 * 2;
  unsigned* ptab = xbf;        // alias: x table dead after layer 1

  const int* src = ei;        // edge_index[0]
  const int* dst = ei + NE;   // edge_index[1]

  hipMemsetAsync(cnt, 0, (size_t)NN * 4, stream);
  build_buckets<<<NSLICE * (NE / CHUNK), 256, 0, stream>>>(src, dst, cnt, buck);
  to_bf16<<<(NN * 32 + 255) / 256, 256, 0, stream>>>(x, xbf);
  transpose_w<<<192, 256, 0, stream>>>(W1l, W1r, W2l, W2r, WT1, WT2p);

  // layer 1: h = relu([mean|x] @ [W1l;W1r] + b1), bf16
  sage_fused<128, true, unsigned short><<<(NN + 63) / 64, 256, 0, stream>>>(
      xbf, cnt, buck, WT1, b1, (unsigned short*)hb);

  // layer 2a: p = h@W2l (bf16 128B rows), out = h@W2r + b2 (f32)
  proj2<<<(NN + 63) / 64, 256, 0, stream>>>(hb, WT2p, b2, ptab, out);

  // layer 2b: out += mean-gather(p)
  gather_add<<<(NN + 63) / 64, 256, 0, stream>>>(ptab, cnt, buck, out);
}